// Round 11
// baseline (244.341 us; speedup 1.0000x reference)
//
#include <hip/hip_runtime.h>

#define N_NODES 16384
#define N_EDGES 262144
#define BATCH   256
#define F_OUT   32
#define K_ORD   4
#define NCHUNK  4      // batch chunks; 64 b-lanes each -> full 128B bf16 gather lines
#define CHUNK   64
#define NPB     8      // nodes per group (8 x 32 lanes = 256 thr)
#define GRID_F  2048   // persistent final blocks
#define NGRP    (N_NODES / NPB)          // 2048 node groups
#define SLOTS   (GRID_F / NCHUNK)        // 512
#define GPB_F   (NGRP / SLOTS)           // 4 groups per final block

typedef float f32x4 __attribute__((ext_vector_type(4)));
typedef float f32x2 __attribute__((ext_vector_type(2)));

__device__ __forceinline__ unsigned short f2bf(float f) {
    unsigned u = __float_as_uint(f);
    return (unsigned short)((u + 0x7FFFu + ((u >> 16) & 1u)) >> 16);
}
__device__ __forceinline__ float bf2f(unsigned v) {   // low 16 bits
    return __uint_as_float(v << 16);
}

// ---------------- transpose: x (B,N) -> xT f32 (N,B) + xb bf16 (N,B) ----------------
__global__ void transpose_kernel(const float* __restrict__ x, float* __restrict__ xT,
                                 unsigned short* __restrict__ xb) {
    __shared__ float tile[32][33];
    int tx = threadIdx.x;          // 0..31
    int ty = threadIdx.y;          // 0..7
    int n0 = blockIdx.x * 32;
    int b0 = blockIdx.y * 32;
#pragma unroll
    for (int j = 0; j < 4; ++j) {
        int b = b0 + ty + j * 8;
        int n = n0 + tx;
        tile[ty + j * 8][tx] = x[(size_t)b * N_NODES + n];
    }
    __syncthreads();
#pragma unroll
    for (int j = 0; j < 4; ++j) {
        int n = n0 + ty + j * 8;
        int b = b0 + tx;
        float v = tile[tx][ty + j * 8];
        xT[(size_t)n * BATCH + b] = v;
        xb[(size_t)n * BATCH + b] = f2bf(v);
    }
}

// ---------------- CSR build (packed: low16 = col, high16 = bf16 val) ----------------
__global__ void hist_kernel(const int* __restrict__ rows, int* __restrict__ count) {
    int e = blockIdx.x * blockDim.x + threadIdx.x;
    if (e < N_EDGES) atomicAdd(&count[rows[e]], 1);
}

__global__ void scan_kernel(int* __restrict__ count, int* __restrict__ row_ptr) {
    __shared__ int part[256];
    int t = threadIdx.x;
    int base = t * 64;
    int loc[64];
    int s = 0;
#pragma unroll
    for (int i = 0; i < 64; ++i) { loc[i] = count[base + i]; s += loc[i]; }
    part[t] = s;
    __syncthreads();
    for (int d = 1; d < 256; d <<= 1) {
        int v = (t >= d) ? part[t - d] : 0;
        __syncthreads();
        part[t] += v;
        __syncthreads();
    }
    int off = part[t] - s;  // exclusive prefix
#pragma unroll
    for (int i = 0; i < 64; ++i) {
        row_ptr[base + i] = off;
        count[base + i] = off;   // becomes the scatter cursor
        off += loc[i];
    }
    if (t == 255) row_ptr[N_NODES] = off;   // == N_EDGES
}

__global__ void scatter_kernel(const int* __restrict__ rows, const int* __restrict__ cols,
                               const float* __restrict__ vals,
                               int* __restrict__ cursor,
                               unsigned* __restrict__ csrp) {
    int e = blockIdx.x * blockDim.x + threadIdx.x;
    if (e < N_EDGES) {
        int r = rows[e];
        int pos = atomicAdd(&cursor[r], 1);
        csrp[pos] = (unsigned)cols[e] | ((unsigned)f2bf(vals[e]) << 16);
    }
}

// ---------------- Chebyshev step: out = c*(L@in - in) - prev ----------------
// bf16 gather operand (inb) + bf16 prev; f32 self + f32 out state.
__global__ void cheb_kernel(const float* __restrict__ in, const unsigned short* __restrict__ inb,
                            const unsigned short* __restrict__ prevb,
                            float* __restrict__ out, unsigned short* __restrict__ outb,
                            const int* __restrict__ row_ptr,
                            const unsigned* __restrict__ csrp, float c) {
    int chunk = blockIdx.x & (NCHUNK - 1);
    int ng    = blockIdx.x >> 2;
    int nsub  = threadIdx.x >> 5;
    int b     = chunk * CHUNK + (threadIdx.x & 31) * 2;
    int n     = ng * NPB + nsub;
    int beg = row_ptr[n], end = row_ptr[n + 1];
    f32x2 acc = (f32x2)(0.f);
    int e = beg;
    for (; e + 3 < end; e += 4) {
        unsigned p0 = csrp[e], p1 = csrp[e + 1], p2 = csrp[e + 2], p3 = csrp[e + 3];
        unsigned g0 = *(const unsigned*)&inb[(size_t)(p0 & 0xFFFF) * BATCH + b];
        unsigned g1 = *(const unsigned*)&inb[(size_t)(p1 & 0xFFFF) * BATCH + b];
        unsigned g2 = *(const unsigned*)&inb[(size_t)(p2 & 0xFFFF) * BATCH + b];
        unsigned g3 = *(const unsigned*)&inb[(size_t)(p3 & 0xFFFF) * BATCH + b];
        float v0 = bf2f(p0 >> 16), v1 = bf2f(p1 >> 16), v2 = bf2f(p2 >> 16), v3 = bf2f(p3 >> 16);
        acc.x += v0 * bf2f(g0 & 0xFFFF) + v1 * bf2f(g1 & 0xFFFF)
               + v2 * bf2f(g2 & 0xFFFF) + v3 * bf2f(g3 & 0xFFFF);
        acc.y += v0 * bf2f(g0 >> 16) + v1 * bf2f(g1 >> 16)
               + v2 * bf2f(g2 >> 16) + v3 * bf2f(g3 >> 16);
    }
    for (; e < end; ++e) {
        unsigned p = csrp[e];
        unsigned g = *(const unsigned*)&inb[(size_t)(p & 0xFFFF) * BATCH + b];
        float v = bf2f(p >> 16);
        acc.x += v * bf2f(g & 0xFFFF);
        acc.y += v * bf2f(g >> 16);
    }
    size_t idx = (size_t)n * BATCH + b;
    f32x2 self = *(const f32x2*)&in[idx];
    f32x2 o = c * (acc - self);
    if (prevb) {
        unsigned pv = *(const unsigned*)&prevb[idx];
        o.x -= bf2f(pv & 0xFFFF);
        o.y -= bf2f(pv >> 16);
    }
    *(f32x2*)&out[idx] = o;
    *(unsigned*)&outb[idx] = (unsigned)f2bf(o.x) | ((unsigned)f2bf(o.y) << 16);
}

// ---------------- fused final: T3 = 2*(L@T2 - T2) - T1 ; y = [T0..T3] @ W^T + b ------
// Persistent, double-buffered: stores for group g issued (fire-and-forget NT) BEFORE the
// gathers of group g+1, so HBM write drain overlaps LLC gather latency.
__global__ void __launch_bounds__(256, 8)
final_kernel(const unsigned short* __restrict__ t0b, const unsigned short* __restrict__ t1b,
             const float* __restrict__ t2, const unsigned short* __restrict__ t2b,
             const int* __restrict__ row_ptr,
             const unsigned* __restrict__ csrp,
             const float* __restrict__ weight, const float* __restrict__ bias,
             float* __restrict__ out) {
    __shared__ float w[F_OUT * K_ORD];
    __shared__ float bb[F_OUT];
    __shared__ f32x4 tval[2][NPB][CHUNK + 1];
    int tid = threadIdx.x;
    if (tid < F_OUT * K_ORD) w[tid] = weight[tid];
    if (tid < F_OUT) bb[tid] = bias[tid];
    __syncthreads();

    int chunk = blockIdx.x & (NCHUNK - 1);
    int bslot = blockIdx.x >> 2;            // 0..511

    // phase-1 mapping
    int p1_nsub = tid >> 5;
    int p1_bi   = (tid & 31) * 2;
    int p1_b    = chunk * CHUNK + p1_bi;
    // phase-2 mapping
    int f = (tid & 7) * 4;
    f32x4 w0 = *(const f32x4*)&w[(f + 0) * 4];
    f32x4 w1 = *(const f32x4*)&w[(f + 1) * 4];
    f32x4 w2 = *(const f32x4*)&w[(f + 2) * 4];
    f32x4 w3 = *(const f32x4*)&w[(f + 3) * 4];
    f32x4 b4 = *(const f32x4*)&bb[f];
    int p2_nsub = (tid >> 3) & 7;
    int p2_wv   = tid >> 6;

    auto phase1 = [&](int g, int buf) {
        int n = (bslot + g * SLOTS) * NPB + p1_nsub;
        int beg = row_ptr[n], end = row_ptr[n + 1];
        f32x2 acc = (f32x2)(0.f);
        int e = beg;
        for (; e + 3 < end; e += 4) {
            unsigned p0 = csrp[e], p1 = csrp[e + 1], p2 = csrp[e + 2], p3 = csrp[e + 3];
            unsigned g0 = *(const unsigned*)&t2b[(size_t)(p0 & 0xFFFF) * BATCH + p1_b];
            unsigned g1 = *(const unsigned*)&t2b[(size_t)(p1 & 0xFFFF) * BATCH + p1_b];
            unsigned g2 = *(const unsigned*)&t2b[(size_t)(p2 & 0xFFFF) * BATCH + p1_b];
            unsigned g3 = *(const unsigned*)&t2b[(size_t)(p3 & 0xFFFF) * BATCH + p1_b];
            float v0 = bf2f(p0 >> 16), v1 = bf2f(p1 >> 16), v2 = bf2f(p2 >> 16), v3 = bf2f(p3 >> 16);
            acc.x += v0 * bf2f(g0 & 0xFFFF) + v1 * bf2f(g1 & 0xFFFF)
                   + v2 * bf2f(g2 & 0xFFFF) + v3 * bf2f(g3 & 0xFFFF);
            acc.y += v0 * bf2f(g0 >> 16) + v1 * bf2f(g1 >> 16)
                   + v2 * bf2f(g2 >> 16) + v3 * bf2f(g3 >> 16);
        }
        for (; e < end; ++e) {
            unsigned p = csrp[e];
            unsigned g = *(const unsigned*)&t2b[(size_t)(p & 0xFFFF) * BATCH + p1_b];
            float v = bf2f(p >> 16);
            acc.x += v * bf2f(g & 0xFFFF);
            acc.y += v * bf2f(g >> 16);
        }
        size_t idx = (size_t)n * BATCH + p1_b;
        f32x2 t2v = *(const f32x2*)&t2[idx];
        unsigned u0 = *(const unsigned*)&t0b[idx];
        unsigned u1 = *(const unsigned*)&t1b[idx];
        f32x2 t0v = {bf2f(u0 & 0xFFFF), bf2f(u0 >> 16)};
        f32x2 t1v = {bf2f(u1 & 0xFFFF), bf2f(u1 >> 16)};
        f32x2 t3v = 2.f * (acc - t2v) - t1v;
        tval[buf][p1_nsub][p1_bi]     = (f32x4){t0v.x, t1v.x, t2v.x, t3v.x};
        tval[buf][p1_nsub][p1_bi + 1] = (f32x4){t0v.y, t1v.y, t2v.y, t3v.y};
    };

    phase1(0, 0);
    for (int g = 0; g < GPB_F; ++g) {
        __syncthreads();
        // phase 2: stores for group g (NT, fire-and-forget)
        size_t n = (size_t)((bslot + g * SLOTS) * NPB + p2_nsub);
        int buf = g & 1;
#pragma unroll
        for (int i = 0; i < 16; ++i) {
            int b_idx = i * 4 + p2_wv;                   // 0..63
            size_t b  = (size_t)(chunk * CHUNK + b_idx);
            f32x4 tv = tval[buf][p2_nsub][b_idx];
            f32x4 r;
            r.x = w0.x * tv.x + w0.y * tv.y + w0.z * tv.z + w0.w * tv.w + b4.x;
            r.y = w1.x * tv.x + w1.y * tv.y + w1.z * tv.z + w1.w * tv.w + b4.y;
            r.z = w2.x * tv.x + w2.y * tv.y + w2.z * tv.z + w2.w * tv.w + b4.z;
            r.w = w3.x * tv.x + w3.y * tv.y + w3.z * tv.z + w3.w * tv.w + b4.w;
            __builtin_nontemporal_store(r, (f32x4*)(out + (b * N_NODES + n) * F_OUT + f));
        }
        // phase 1 for group g+1 overlaps the store drain
        if (g + 1 < GPB_F) phase1(g + 1, (g + 1) & 1);
    }
}

extern "C" void kernel_launch(void* const* d_in, const int* in_sizes, int n_in,
                              void* d_out, int out_size, void* d_ws, size_t ws_size,
                              hipStream_t stream) {
    const float* x      = (const float*)d_in[0];
    const float* vals   = (const float*)d_in[1];
    const int*   rows   = (const int*)d_in[2];
    const int*   cols   = (const int*)d_in[3];
    const float* weight = (const float*)d_in[4];
    const float* bias   = (const float*)d_in[5];
    float* out = (float*)d_out;

    const size_t NB = (size_t)N_NODES * BATCH;   // 4,194,304 elements
    float*          xT      = (float*)d_ws;
    float*          t1      = xT + NB;
    float*          t2      = t1 + NB;
    unsigned short* xb      = (unsigned short*)(t2 + NB);
    unsigned short* t1b     = xb + NB;
    unsigned short* t2b     = t1b + NB;
    int*            row_ptr = (int*)(t2b + NB);  // N_NODES+1 (pad to 16448)
    int*            cursor  = row_ptr + 16448;
    unsigned*       csrp    = (unsigned*)(cursor + N_NODES);

    (void)hipMemsetAsync(cursor, 0, N_NODES * sizeof(int), stream);

    transpose_kernel<<<dim3(N_NODES / 32, BATCH / 32), dim3(32, 8), 0, stream>>>(x, xT, xb);
    hist_kernel<<<N_EDGES / 256, 256, 0, stream>>>(rows, cursor);
    scan_kernel<<<1, 256, 0, stream>>>(cursor, row_ptr);
    scatter_kernel<<<N_EDGES / 256, 256, 0, stream>>>(rows, cols, vals, cursor, csrp);

    const int GRID = (N_NODES / NPB) * NCHUNK;   // 8192 blocks
    cheb_kernel<<<GRID, 256, 0, stream>>>(xT, xb, nullptr, t1, t1b, row_ptr, csrp, 1.f);
    cheb_kernel<<<GRID, 256, 0, stream>>>(t1, t1b, xb, t2, t2b, row_ptr, csrp, 2.f);
    final_kernel<<<GRID_F, 256, 0, stream>>>(xb, t1b, t2, t2b, row_ptr, csrp,
                                             weight, bias, out);
}

// Round 12
// 211.844 us; speedup vs baseline: 1.1534x; 1.1534x over previous
//
#include <hip/hip_runtime.h>

#define N_NODES 16384
#define N_EDGES 262144
#define BATCH   256
#define F_OUT   32
#define K_ORD   4
#define NCHUNK  4      // batch chunks; 64 b-lanes each -> full 128B bf16 gather lines
#define CHUNK   64
#define NPB     8      // nodes per block

typedef float f32x4 __attribute__((ext_vector_type(4)));
typedef float f32x2 __attribute__((ext_vector_type(2)));

__device__ __forceinline__ unsigned short f2bf(float f) {
    unsigned u = __float_as_uint(f);
    return (unsigned short)((u + 0x7FFFu + ((u >> 16) & 1u)) >> 16);
}
__device__ __forceinline__ float bf2f(unsigned v) {   // low 16 bits
    return __uint_as_float(v << 16);
}

// ---------------- transpose: x (B,N) -> xT f32 (N,B) + xb bf16 (N,B) ----------------
__global__ void transpose_kernel(const float* __restrict__ x, float* __restrict__ xT,
                                 unsigned short* __restrict__ xb) {
    __shared__ float tile[32][33];
    int tx = threadIdx.x;          // 0..31
    int ty = threadIdx.y;          // 0..7
    int n0 = blockIdx.x * 32;
    int b0 = blockIdx.y * 32;
#pragma unroll
    for (int j = 0; j < 4; ++j) {
        int b = b0 + ty + j * 8;
        int n = n0 + tx;
        tile[ty + j * 8][tx] = x[(size_t)b * N_NODES + n];
    }
    __syncthreads();
#pragma unroll
    for (int j = 0; j < 4; ++j) {
        int n = n0 + ty + j * 8;
        int b = b0 + tx;
        float v = tile[tx][ty + j * 8];
        xT[(size_t)n * BATCH + b] = v;
        xb[(size_t)n * BATCH + b] = f2bf(v);
    }
}

// ---------------- CSR build (packed: low16 = col, high16 = bf16 val) ----------------
__global__ void hist_kernel(const int* __restrict__ rows, int* __restrict__ count) {
    int e = blockIdx.x * blockDim.x + threadIdx.x;
    if (e < N_EDGES) atomicAdd(&count[rows[e]], 1);
}

__global__ void scan_kernel(int* __restrict__ count, int* __restrict__ row_ptr) {
    __shared__ int part[256];
    int t = threadIdx.x;
    int base = t * 64;
    int loc[64];
    int s = 0;
#pragma unroll
    for (int i = 0; i < 64; ++i) { loc[i] = count[base + i]; s += loc[i]; }
    part[t] = s;
    __syncthreads();
    for (int d = 1; d < 256; d <<= 1) {
        int v = (t >= d) ? part[t - d] : 0;
        __syncthreads();
        part[t] += v;
        __syncthreads();
    }
    int off = part[t] - s;  // exclusive prefix
#pragma unroll
    for (int i = 0; i < 64; ++i) {
        row_ptr[base + i] = off;
        count[base + i] = off;   // becomes the scatter cursor
        off += loc[i];
    }
    if (t == 255) row_ptr[N_NODES] = off;   // == N_EDGES
}

__global__ void scatter_kernel(const int* __restrict__ rows, const int* __restrict__ cols,
                               const float* __restrict__ vals,
                               int* __restrict__ cursor,
                               unsigned* __restrict__ csrp) {
    int e = blockIdx.x * blockDim.x + threadIdx.x;
    if (e < N_EDGES) {
        int r = rows[e];
        int pos = atomicAdd(&cursor[r], 1);
        csrp[pos] = (unsigned)cols[e] | ((unsigned)f2bf(vals[e]) << 16);
    }
}

// ---------------- Chebyshev step: out = c*(L@in - in) - prev ----------------
// bf16 gather operand (inb) + bf16 prev; f32 self; f32 out optional (outb always).
__global__ void cheb_kernel(const float* __restrict__ in, const unsigned short* __restrict__ inb,
                            const unsigned short* __restrict__ prevb,
                            float* __restrict__ out, unsigned short* __restrict__ outb,
                            const int* __restrict__ row_ptr,
                            const unsigned* __restrict__ csrp, float c) {
    int chunk = blockIdx.x & (NCHUNK - 1);
    int ng    = blockIdx.x >> 2;
    int nsub  = threadIdx.x >> 5;
    int b     = chunk * CHUNK + (threadIdx.x & 31) * 2;
    int n     = ng * NPB + nsub;
    int beg = row_ptr[n], end = row_ptr[n + 1];
    f32x2 acc = (f32x2)(0.f);
    int e = beg;
    for (; e + 3 < end; e += 4) {
        unsigned p0 = csrp[e], p1 = csrp[e + 1], p2 = csrp[e + 2], p3 = csrp[e + 3];
        unsigned g0 = *(const unsigned*)&inb[(size_t)(p0 & 0xFFFF) * BATCH + b];
        unsigned g1 = *(const unsigned*)&inb[(size_t)(p1 & 0xFFFF) * BATCH + b];
        unsigned g2 = *(const unsigned*)&inb[(size_t)(p2 & 0xFFFF) * BATCH + b];
        unsigned g3 = *(const unsigned*)&inb[(size_t)(p3 & 0xFFFF) * BATCH + b];
        float v0 = bf2f(p0 >> 16), v1 = bf2f(p1 >> 16), v2 = bf2f(p2 >> 16), v3 = bf2f(p3 >> 16);
        acc.x += v0 * bf2f(g0 & 0xFFFF) + v1 * bf2f(g1 & 0xFFFF)
               + v2 * bf2f(g2 & 0xFFFF) + v3 * bf2f(g3 & 0xFFFF);
        acc.y += v0 * bf2f(g0 >> 16) + v1 * bf2f(g1 >> 16)
               + v2 * bf2f(g2 >> 16) + v3 * bf2f(g3 >> 16);
    }
    for (; e < end; ++e) {
        unsigned p = csrp[e];
        unsigned g = *(const unsigned*)&inb[(size_t)(p & 0xFFFF) * BATCH + b];
        float v = bf2f(p >> 16);
        acc.x += v * bf2f(g & 0xFFFF);
        acc.y += v * bf2f(g >> 16);
    }
    size_t idx = (size_t)n * BATCH + b;
    f32x2 self = *(const f32x2*)&in[idx];
    f32x2 o = c * (acc - self);
    if (prevb) {
        unsigned pv = *(const unsigned*)&prevb[idx];
        o.x -= bf2f(pv & 0xFFFF);
        o.y -= bf2f(pv >> 16);
    }
    if (out) *(f32x2*)&out[idx] = o;
    *(unsigned*)&outb[idx] = (unsigned)f2bf(o.x) | ((unsigned)f2bf(o.y) << 16);
}

// ---------------- fused final: T3 = 2*(L@T2 - T2) - T1 ; y = [T0..T3] @ W^T + b ------
// Round-10 structure (8192 independent blocks). All term reads from bf16 shadows.
__global__ void final_kernel(const unsigned short* __restrict__ t0b,
                             const unsigned short* __restrict__ t1b,
                             const unsigned short* __restrict__ t2b,
                             const int* __restrict__ row_ptr,
                             const unsigned* __restrict__ csrp,
                             const float* __restrict__ weight, const float* __restrict__ bias,
                             float* __restrict__ out) {
    __shared__ float w[F_OUT * K_ORD];
    __shared__ float bb[F_OUT];
    __shared__ f32x4 tval[NPB][CHUNK + 1];
    int tid = threadIdx.x;
    if (tid < F_OUT * K_ORD) w[tid] = weight[tid];
    if (tid < F_OUT) bb[tid] = bias[tid];
    __syncthreads();

    int chunk = blockIdx.x & (NCHUNK - 1);
    int ng    = blockIdx.x >> 2;
    {
        int nsub = tid >> 5;
        int bi   = (tid & 31) * 2;
        int b    = chunk * CHUNK + bi;
        int n    = ng * NPB + nsub;
        int beg = row_ptr[n], end = row_ptr[n + 1];
        f32x2 acc = (f32x2)(0.f);
        int e = beg;
        for (; e + 3 < end; e += 4) {
            unsigned p0 = csrp[e], p1 = csrp[e + 1], p2 = csrp[e + 2], p3 = csrp[e + 3];
            unsigned g0 = *(const unsigned*)&t2b[(size_t)(p0 & 0xFFFF) * BATCH + b];
            unsigned g1 = *(const unsigned*)&t2b[(size_t)(p1 & 0xFFFF) * BATCH + b];
            unsigned g2 = *(const unsigned*)&t2b[(size_t)(p2 & 0xFFFF) * BATCH + b];
            unsigned g3 = *(const unsigned*)&t2b[(size_t)(p3 & 0xFFFF) * BATCH + b];
            float v0 = bf2f(p0 >> 16), v1 = bf2f(p1 >> 16), v2 = bf2f(p2 >> 16), v3 = bf2f(p3 >> 16);
            acc.x += v0 * bf2f(g0 & 0xFFFF) + v1 * bf2f(g1 & 0xFFFF)
                   + v2 * bf2f(g2 & 0xFFFF) + v3 * bf2f(g3 & 0xFFFF);
            acc.y += v0 * bf2f(g0 >> 16) + v1 * bf2f(g1 >> 16)
                   + v2 * bf2f(g2 >> 16) + v3 * bf2f(g3 >> 16);
        }
        for (; e < end; ++e) {
            unsigned p = csrp[e];
            unsigned g = *(const unsigned*)&t2b[(size_t)(p & 0xFFFF) * BATCH + b];
            float v = bf2f(p >> 16);
            acc.x += v * bf2f(g & 0xFFFF);
            acc.y += v * bf2f(g >> 16);
        }
        size_t idx = (size_t)n * BATCH + b;
        unsigned u0 = *(const unsigned*)&t0b[idx];
        unsigned u1 = *(const unsigned*)&t1b[idx];
        unsigned u2 = *(const unsigned*)&t2b[idx];
        f32x2 t0v = {bf2f(u0 & 0xFFFF), bf2f(u0 >> 16)};
        f32x2 t1v = {bf2f(u1 & 0xFFFF), bf2f(u1 >> 16)};
        f32x2 t2v = {bf2f(u2 & 0xFFFF), bf2f(u2 >> 16)};
        f32x2 t3v = 2.f * (acc - t2v) - t1v;
        tval[nsub][bi]     = (f32x4){t0v.x, t1v.x, t2v.x, t3v.x};
        tval[nsub][bi + 1] = (f32x4){t0v.y, t1v.y, t2v.y, t3v.y};
    }
    __syncthreads();

    // phase 2: 8 nodes x 64 b x 32 f floats = 4096 f32x4; 16 per thread.
    // At fixed i a wave covers nsub 0..7 x f 0..31 -> 1KB contiguous per store.
    int f = (tid & 7) * 4;
    f32x4 w0 = *(const f32x4*)&w[(f + 0) * 4];
    f32x4 w1 = *(const f32x4*)&w[(f + 1) * 4];
    f32x4 w2 = *(const f32x4*)&w[(f + 2) * 4];
    f32x4 w3 = *(const f32x4*)&w[(f + 3) * 4];
    f32x4 b4 = *(const f32x4*)&bb[f];
    int nsub = (tid >> 3) & 7;
    int wv   = tid >> 6;
    size_t n = (size_t)(ng * NPB + nsub);
#pragma unroll
    for (int i = 0; i < 16; ++i) {
        int b_idx = i * 4 + wv;                      // 0..63
        size_t b  = (size_t)(chunk * CHUNK + b_idx);
        f32x4 tv = tval[nsub][b_idx];
        f32x4 r;
        r.x = w0.x * tv.x + w0.y * tv.y + w0.z * tv.z + w0.w * tv.w + b4.x;
        r.y = w1.x * tv.x + w1.y * tv.y + w1.z * tv.z + w1.w * tv.w + b4.y;
        r.z = w2.x * tv.x + w2.y * tv.y + w2.z * tv.z + w2.w * tv.w + b4.z;
        r.w = w3.x * tv.x + w3.y * tv.y + w3.z * tv.z + w3.w * tv.w + b4.w;
        __builtin_nontemporal_store(r, (f32x4*)(out + (b * N_NODES + n) * F_OUT + f));
    }
}

extern "C" void kernel_launch(void* const* d_in, const int* in_sizes, int n_in,
                              void* d_out, int out_size, void* d_ws, size_t ws_size,
                              hipStream_t stream) {
    const float* x      = (const float*)d_in[0];
    const float* vals   = (const float*)d_in[1];
    const int*   rows   = (const int*)d_in[2];
    const int*   cols   = (const int*)d_in[3];
    const float* weight = (const float*)d_in[4];
    const float* bias   = (const float*)d_in[5];
    float* out = (float*)d_out;

    const size_t NB = (size_t)N_NODES * BATCH;   // 4,194,304 elements
    float*          xT      = (float*)d_ws;
    float*          t1      = xT + NB;
    unsigned short* xb      = (unsigned short*)(t1 + NB);
    unsigned short* t1b     = xb + NB;
    unsigned short* t2b     = t1b + NB;
    int*            row_ptr = (int*)(t2b + NB);  // N_NODES+1 (pad to 16448)
    int*            cursor  = row_ptr + 16448;
    unsigned*       csrp    = (unsigned*)(cursor + N_NODES);

    (void)hipMemsetAsync(cursor, 0, N_NODES * sizeof(int), stream);

    transpose_kernel<<<dim3(N_NODES / 32, BATCH / 32), dim3(32, 8), 0, stream>>>(x, xT, xb);
    hist_kernel<<<N_EDGES / 256, 256, 0, stream>>>(rows, cursor);
    scan_kernel<<<1, 256, 0, stream>>>(cursor, row_ptr);
    scatter_kernel<<<N_EDGES / 256, 256, 0, stream>>>(rows, cols, vals, cursor, csrp);

    const int GRID = (N_NODES / NPB) * NCHUNK;   // 8192 blocks
    cheb_kernel<<<GRID, 256, 0, stream>>>(xT, xb, nullptr, t1, t1b, row_ptr, csrp, 1.f);
    cheb_kernel<<<GRID, 256, 0, stream>>>(t1, t1b, xb, nullptr, t2b, row_ptr, csrp, 2.f);
    final_kernel<<<GRID, 256, 0, stream>>>(xb, t1b, t2b, row_ptr, csrp,
                                           weight, bias, out);
}

// Round 13
// 202.970 us; speedup vs baseline: 1.2038x; 1.0437x over previous
//
#include <hip/hip_runtime.h>

#define N_NODES 16384
#define N_EDGES 262144
#define BATCH   256
#define F_OUT   32
#define K_ORD   4
#define NCHUNK  4      // batch chunks; 64 b-lanes each -> full 128B bf16 gather lines
#define CHUNK   64
#define NPB     8      // nodes per block

typedef float f32x4 __attribute__((ext_vector_type(4)));
typedef float f32x2 __attribute__((ext_vector_type(2)));

__device__ __forceinline__ unsigned short f2bf(float f) {
    unsigned u = __float_as_uint(f);
    return (unsigned short)((u + 0x7FFFu + ((u >> 16) & 1u)) >> 16);
}
__device__ __forceinline__ float bf2f(unsigned v) {   // low 16 bits
    return __uint_as_float(v << 16);
}

// ---------------- transpose: x (B,N) -> xb bf16 (N,B) ----------------
__global__ void transpose_kernel(const float* __restrict__ x,
                                 unsigned short* __restrict__ xb) {
    __shared__ float tile[32][33];
    int tx = threadIdx.x;          // 0..31
    int ty = threadIdx.y;          // 0..7
    int n0 = blockIdx.x * 32;
    int b0 = blockIdx.y * 32;
#pragma unroll
    for (int j = 0; j < 4; ++j) {
        int b = b0 + ty + j * 8;
        int n = n0 + tx;
        tile[ty + j * 8][tx] = x[(size_t)b * N_NODES + n];
    }
    __syncthreads();
#pragma unroll
    for (int j = 0; j < 4; ++j) {
        int n = n0 + ty + j * 8;
        int b = b0 + tx;
        xb[(size_t)n * BATCH + b] = f2bf(tile[tx][ty + j * 8]);
    }
}

// ---------------- CSR build (packed: low16 = col, high16 = bf16 val) ----------------
__global__ void hist_kernel(const int* __restrict__ rows, int* __restrict__ count) {
    int e = blockIdx.x * blockDim.x + threadIdx.x;
    if (e < N_EDGES) atomicAdd(&count[rows[e]], 1);
}

__global__ void scan_kernel(int* __restrict__ count, int* __restrict__ row_ptr) {
    __shared__ int part[256];
    int t = threadIdx.x;
    int base = t * 64;
    int loc[64];
    int s = 0;
#pragma unroll
    for (int i = 0; i < 64; ++i) { loc[i] = count[base + i]; s += loc[i]; }
    part[t] = s;
    __syncthreads();
    for (int d = 1; d < 256; d <<= 1) {
        int v = (t >= d) ? part[t - d] : 0;
        __syncthreads();
        part[t] += v;
        __syncthreads();
    }
    int off = part[t] - s;  // exclusive prefix
#pragma unroll
    for (int i = 0; i < 64; ++i) {
        row_ptr[base + i] = off;
        count[base + i] = off;   // becomes the scatter cursor
        off += loc[i];
    }
    if (t == 255) row_ptr[N_NODES] = off;   // == N_EDGES
}

__global__ void scatter_kernel(const int* __restrict__ rows, const int* __restrict__ cols,
                               const float* __restrict__ vals,
                               int* __restrict__ cursor,
                               unsigned* __restrict__ csrp) {
    int e = blockIdx.x * blockDim.x + threadIdx.x;
    if (e < N_EDGES) {
        int r = rows[e];
        int pos = atomicAdd(&cursor[r], 1);
        csrp[pos] = (unsigned)cols[e] | ((unsigned)f2bf(vals[e]) << 16);
    }
}

// ---------------- Chebyshev step: out = c*(L@in - in) - prev, all-bf16 state --------
__global__ void cheb_kernel(const unsigned short* __restrict__ inb,
                            const unsigned short* __restrict__ prevb,
                            unsigned short* __restrict__ outb,
                            const int* __restrict__ row_ptr,
                            const unsigned* __restrict__ csrp, float c) {
    int chunk = blockIdx.x & (NCHUNK - 1);
    int ng    = blockIdx.x >> 2;
    int nsub  = threadIdx.x >> 5;
    int b     = chunk * CHUNK + (threadIdx.x & 31) * 2;
    int n     = ng * NPB + nsub;
    int beg = row_ptr[n], end = row_ptr[n + 1];
    f32x2 acc = (f32x2)(0.f);
    int e = beg;
    for (; e + 3 < end; e += 4) {
        unsigned p0 = csrp[e], p1 = csrp[e + 1], p2 = csrp[e + 2], p3 = csrp[e + 3];
        unsigned g0 = *(const unsigned*)&inb[(size_t)(p0 & 0xFFFF) * BATCH + b];
        unsigned g1 = *(const unsigned*)&inb[(size_t)(p1 & 0xFFFF) * BATCH + b];
        unsigned g2 = *(const unsigned*)&inb[(size_t)(p2 & 0xFFFF) * BATCH + b];
        unsigned g3 = *(const unsigned*)&inb[(size_t)(p3 & 0xFFFF) * BATCH + b];
        float v0 = bf2f(p0 >> 16), v1 = bf2f(p1 >> 16), v2 = bf2f(p2 >> 16), v3 = bf2f(p3 >> 16);
        acc.x += v0 * bf2f(g0 & 0xFFFF) + v1 * bf2f(g1 & 0xFFFF)
               + v2 * bf2f(g2 & 0xFFFF) + v3 * bf2f(g3 & 0xFFFF);
        acc.y += v0 * bf2f(g0 >> 16) + v1 * bf2f(g1 >> 16)
               + v2 * bf2f(g2 >> 16) + v3 * bf2f(g3 >> 16);
    }
    for (; e < end; ++e) {
        unsigned p = csrp[e];
        unsigned g = *(const unsigned*)&inb[(size_t)(p & 0xFFFF) * BATCH + b];
        float v = bf2f(p >> 16);
        acc.x += v * bf2f(g & 0xFFFF);
        acc.y += v * bf2f(g >> 16);
    }
    size_t idx = (size_t)n * BATCH + b;
    unsigned sv = *(const unsigned*)&inb[idx];
    f32x2 self = {bf2f(sv & 0xFFFF), bf2f(sv >> 16)};
    f32x2 o = c * (acc - self);
    if (prevb) {
        unsigned pv = *(const unsigned*)&prevb[idx];
        o.x -= bf2f(pv & 0xFFFF);
        o.y -= bf2f(pv >> 16);
    }
    *(unsigned*)&outb[idx] = (unsigned)f2bf(o.x) | ((unsigned)f2bf(o.y) << 16);
}

// ---------------- fused final: T3 = 2*(L@T2 - T2) - T1 ; y = [T0..T3] @ W^T + b ------
__global__ void final_kernel(const unsigned short* __restrict__ t0b,
                             const unsigned short* __restrict__ t1b,
                             const unsigned short* __restrict__ t2b,
                             const int* __restrict__ row_ptr,
                             const unsigned* __restrict__ csrp,
                             const float* __restrict__ weight, const float* __restrict__ bias,
                             float* __restrict__ out) {
    __shared__ float w[F_OUT * K_ORD];
    __shared__ float bb[F_OUT];
    __shared__ f32x4 tval[NPB][CHUNK + 1];
    int tid = threadIdx.x;
    if (tid < F_OUT * K_ORD) w[tid] = weight[tid];
    if (tid < F_OUT) bb[tid] = bias[tid];
    __syncthreads();

    int chunk = blockIdx.x & (NCHUNK - 1);
    int ng    = blockIdx.x >> 2;
    {
        int nsub = tid >> 5;
        int bi   = (tid & 31) * 2;
        int b    = chunk * CHUNK + bi;
        int n    = ng * NPB + nsub;
        int beg = row_ptr[n], end = row_ptr[n + 1];
        f32x2 acc = (f32x2)(0.f);
        int e = beg;
        for (; e + 3 < end; e += 4) {
            unsigned p0 = csrp[e], p1 = csrp[e + 1], p2 = csrp[e + 2], p3 = csrp[e + 3];
            unsigned g0 = *(const unsigned*)&t2b[(size_t)(p0 & 0xFFFF) * BATCH + b];
            unsigned g1 = *(const unsigned*)&t2b[(size_t)(p1 & 0xFFFF) * BATCH + b];
            unsigned g2 = *(const unsigned*)&t2b[(size_t)(p2 & 0xFFFF) * BATCH + b];
            unsigned g3 = *(const unsigned*)&t2b[(size_t)(p3 & 0xFFFF) * BATCH + b];
            float v0 = bf2f(p0 >> 16), v1 = bf2f(p1 >> 16), v2 = bf2f(p2 >> 16), v3 = bf2f(p3 >> 16);
            acc.x += v0 * bf2f(g0 & 0xFFFF) + v1 * bf2f(g1 & 0xFFFF)
                   + v2 * bf2f(g2 & 0xFFFF) + v3 * bf2f(g3 & 0xFFFF);
            acc.y += v0 * bf2f(g0 >> 16) + v1 * bf2f(g1 >> 16)
                   + v2 * bf2f(g2 >> 16) + v3 * bf2f(g3 >> 16);
        }
        for (; e < end; ++e) {
            unsigned p = csrp[e];
            unsigned g = *(const unsigned*)&t2b[(size_t)(p & 0xFFFF) * BATCH + b];
            float v = bf2f(p >> 16);
            acc.x += v * bf2f(g & 0xFFFF);
            acc.y += v * bf2f(g >> 16);
        }
        size_t idx = (size_t)n * BATCH + b;
        unsigned u0 = *(const unsigned*)&t0b[idx];
        unsigned u1 = *(const unsigned*)&t1b[idx];
        unsigned u2 = *(const unsigned*)&t2b[idx];
        f32x2 t0v = {bf2f(u0 & 0xFFFF), bf2f(u0 >> 16)};
        f32x2 t1v = {bf2f(u1 & 0xFFFF), bf2f(u1 >> 16)};
        f32x2 t2v = {bf2f(u2 & 0xFFFF), bf2f(u2 >> 16)};
        f32x2 t3v = 2.f * (acc - t2v) - t1v;
        tval[nsub][bi]     = (f32x4){t0v.x, t1v.x, t2v.x, t3v.x};
        tval[nsub][bi + 1] = (f32x4){t0v.y, t1v.y, t2v.y, t3v.y};
    }
    __syncthreads();

    // phase 2: 8 nodes x 64 b x 32 f floats = 4096 f32x4; 16 per thread.
    // At fixed i a wave covers nsub 0..7 x f 0..31 -> 1KB contiguous per store.
    int f = (tid & 7) * 4;
    f32x4 w0 = *(const f32x4*)&w[(f + 0) * 4];
    f32x4 w1 = *(const f32x4*)&w[(f + 1) * 4];
    f32x4 w2 = *(const f32x4*)&w[(f + 2) * 4];
    f32x4 w3 = *(const f32x4*)&w[(f + 3) * 4];
    f32x4 b4 = *(const f32x4*)&bb[f];
    int nsub = (tid >> 3) & 7;
    int wv   = tid >> 6;
    size_t n = (size_t)(ng * NPB + nsub);
#pragma unroll
    for (int i = 0; i < 16; ++i) {
        int b_idx = i * 4 + wv;                      // 0..63
        size_t b  = (size_t)(chunk * CHUNK + b_idx);
        f32x4 tv = tval[nsub][b_idx];
        f32x4 r;
        r.x = w0.x * tv.x + w0.y * tv.y + w0.z * tv.z + w0.w * tv.w + b4.x;
        r.y = w1.x * tv.x + w1.y * tv.y + w1.z * tv.z + w1.w * tv.w + b4.y;
        r.z = w2.x * tv.x + w2.y * tv.y + w2.z * tv.z + w2.w * tv.w + b4.z;
        r.w = w3.x * tv.x + w3.y * tv.y + w3.z * tv.z + w3.w * tv.w + b4.w;
        __builtin_nontemporal_store(r, (f32x4*)(out + (b * N_NODES + n) * F_OUT + f));
    }
}

extern "C" void kernel_launch(void* const* d_in, const int* in_sizes, int n_in,
                              void* d_out, int out_size, void* d_ws, size_t ws_size,
                              hipStream_t stream) {
    const float* x      = (const float*)d_in[0];
    const float* vals   = (const float*)d_in[1];
    const int*   rows   = (const int*)d_in[2];
    const int*   cols   = (const int*)d_in[3];
    const float* weight = (const float*)d_in[4];
    const float* bias   = (const float*)d_in[5];
    float* out = (float*)d_out;

    const size_t NB = (size_t)N_NODES * BATCH;   // 4,194,304 elements
    unsigned short* xb      = (unsigned short*)d_ws;
    unsigned short* t1b     = xb + NB;
    unsigned short* t2b     = t1b + NB;
    int*            row_ptr = (int*)(t2b + NB); // N_NODES+1 (pad to 16448)
    int*            cursor  = row_ptr + 16448;
    unsigned*       csrp    = (unsigned*)(cursor + N_NODES);

    (void)hipMemsetAsync(cursor, 0, N_NODES * sizeof(int), stream);

    transpose_kernel<<<dim3(N_NODES / 32, BATCH / 32), dim3(32, 8), 0, stream>>>(x, xb);
    hist_kernel<<<N_EDGES / 256, 256, 0, stream>>>(rows, cursor);
    scan_kernel<<<1, 256, 0, stream>>>(cursor, row_ptr);
    scatter_kernel<<<N_EDGES / 256, 256, 0, stream>>>(rows, cols, vals, cursor, csrp);

    const int GRID = (N_NODES / NPB) * NCHUNK;   // 8192 blocks
    cheb_kernel<<<GRID, 256, 0, stream>>>(xb, nullptr, t1b, row_ptr, csrp, 1.f);
    cheb_kernel<<<GRID, 256, 0, stream>>>(t1b, xb, t2b, row_ptr, csrp, 2.f);
    final_kernel<<<GRID, 256, 0, stream>>>(xb, t1b, t2b, row_ptr, csrp,
                                           weight, bias, out);
}